// Round 12
// baseline (581.190 us; speedup 1.0000x reference)
//
#include <hip/hip_runtime.h>
#include <math.h>

#define NN 25000
#define NE 400000

static constexpr float C_S_ = 0.3826834323650898f;   // sin(pi/8)
static constexpr float C_X_ = 0.9238795325112867f;   // cos(pi/8)
static constexpr float Q_   = 0.25f;                 // 1/sqrt(16)
static constexpr float Q_S3 = 0.25f * 0.5773502691896258f; // Q / sqrt(3)

typedef __attribute__((ext_vector_type(8))) short bf16x8;
typedef __attribute__((ext_vector_type(4))) float f32x4;

__device__ inline unsigned short f2bf(float f) {
    union { float f; unsigned u; } v; v.f = f;
    unsigned r = v.u + 0x7fffu + ((v.u >> 16) & 1u);   // RNE
    return (unsigned short)(r >> 16);
}
__device__ inline float bf2f(unsigned short s) {
    union { unsigned u; float f; } v; v.u = ((unsigned)s) << 16;
    return v.f;
}

// ---------------- K0: pack weights --------------------------------------------
__global__ void k_pack(const float* __restrict__ Wfc2,
                       const float* __restrict__ Wsa, const float* __restrict__ Wsc,
                       const float* __restrict__ W1sa, const float* __restrict__ W1sc, float* __restrict__ W4s,
                       const float* __restrict__ Wva, const float* __restrict__ Wvc,
                       const float* __restrict__ W1va, const float* __restrict__ W1vc, float* __restrict__ W4v,
                       const float* __restrict__ Wl2sa, const float* __restrict__ Wl2sc,
                       const float* __restrict__ Wl2va, const float* __restrict__ Wl2vc,
                       const float* __restrict__ Wl3s, const float* __restrict__ Wl3v,
                       unsigned short* __restrict__ Wfragb,
                       unsigned short* __restrict__ WsabF, unsigned short* __restrict__ WvabF,
                       unsigned short* __restrict__ Wl3sF, unsigned short* __restrict__ Wl3vF)
{
    int t = blockIdx.x * blockDim.x + threadIdx.x;
    if (t < 4096) {
        int k = t >> 6, d = t & 63;
        ((float4*)W4s)[k*64+d] = make_float4(Wsa[k*64+d], Wsc[k*64+d], W1sa[k*64+d], W1sc[k*64+d]);
        return;
    }
    t -= 4096;
    if (t < 1024) {
        int u = t >> 5, o = t & 31;
        ((float4*)W4v)[u*32+o] = make_float4(Wva[u*32+o], Wvc[u*32+o], W1va[u*32+o], W1vc[u*32+o]);
        return;
    }
    t -= 1024;
    if (t < 24576) {
        int i = t & 7, l = (t >> 3) & 63, ks = (t >> 9) & 3, nt = t >> 11;
        int k = ks * 32 + ((l >> 4) << 3) + i;
        int n = nt * 16 + (l & 15);
        Wfragb[t] = (k < 100) ? f2bf(Wfc2[k * 192 + n]) : (unsigned short)0;
        return;
    }
    t -= 24576;
    if (t < 18432) {
        int i = t & 7, l = (t >> 3) & 63, rem = t >> 9;
        int ks = rem % 6, nt = rem / 6;
        int k = ks * 32 + ((l >> 4) << 3) + i;
        int n = nt * 16 + (l & 15);
        WsabF[t] = f2bf(k < 96 ? Wl2sa[k * 96 + n] : Wl2sc[(k - 96) * 96 + n]);
        return;
    }
    t -= 18432;
    if (t < 18432) {
        int i = t & 7, l = (t >> 3) & 63, rem = t >> 9;
        int ks = rem % 6, nt = rem / 6;
        int k = ks * 32 + ((l >> 4) << 3) + i;
        int n = nt * 16 + (l & 15);
        WvabF[t] = f2bf(k < 96 ? Wl2va[k * 96 + n] : Wl2vc[(k - 96) * 96 + n]);
        return;
    }
    t -= 18432;
    if (t < 6144) {
        int i = t & 7, l = (t >> 3) & 63, rem = t >> 9;
        int ks = rem % 3, nt = rem / 3;
        int k = ks * 32 + ((l >> 4) << 3) + i;
        int n = nt * 16 + (l & 15);
        Wl3sF[t] = f2bf(Wl3s[k * 64 + n]);
        return;
    }
    t -= 6144;
    if (t < 3072) {
        int i = t & 7, l = (t >> 3) & 63, rem = t >> 9;
        int ks = rem % 3, nt = rem / 3;
        int k = ks * 32 + ((l >> 4) << 3) + i;
        int n = nt * 16 + (l & 15);
        Wl3vF[t] = f2bf(Wl3v[k * 32 + n]);
        return;
    }
}

// ---------------- K1: node prep (packed weights) ------------------------------
__global__ __launch_bounds__(256) void k_node_prep(
    const float* __restrict__ ni, const float* __restrict__ attr, const float* __restrict__ cattr,
    const float* __restrict__ W4s, const float* __restrict__ W4v,
    float* __restrict__ x1, float* __restrict__ out)
{
    int t = blockIdx.x * blockDim.x + threadIdx.x;
    if (t >= NN * 160) return;
    int n = t / 160, d = t - n * 160;
    float a = attr[n], c = cattr[n];
    const float* row = ni + (size_t)n * 160;
    float ssa = 0.f, ssc = 0.f, s1a = 0.f, s1c = 0.f;
    if (d < 64) {
        const float4* W = (const float4*)W4s;
        #pragma unroll
        for (int k = 0; k < 64; ++k) {
            float x = row[k];
            float4 w = W[k * 64 + d];
            ssa += x * w.x; ssc += x * w.y; s1a += x * w.z; s1c += x * w.w;
        }
    } else {
        int idx = d - 64;
        int o = idx / 3, cc = idx - o * 3;
        const float4* W = (const float4*)W4v;
        #pragma unroll
        for (int u = 0; u < 32; ++u) {
            float x = row[64 + u * 3 + cc];
            float4 w = W[u * 32 + o];
            ssa += x * w.x; ssc += x * w.y; s1a += x * w.z; s1c += x * w.w;
        }
    }
    x1[t]  = a * s1a + c * s1c;
    out[t] = C_S_ * (a * ssa + c * ssc);
}

// ---------------- sort: histogram ---------------------------------------------
__global__ __launch_bounds__(256) void k_hist(const int* __restrict__ edst, int* __restrict__ cnt) {
    int e = blockIdx.x * blockDim.x + threadIdx.x;
    if (e >= NE) return;
    atomicAdd(&cnt[edst[e]], 1);
}

// ---------------- sort: single-block exclusive scan over NN counts ------------
__global__ __launch_bounds__(1024) void k_scan(const int* __restrict__ cnt,
                                               int* __restrict__ start, int* __restrict__ cursor) {
    __shared__ int wsum[16];
    __shared__ int carry_s;
    int lane = threadIdx.x & 63, wid = threadIdx.x >> 6;
    if (threadIdx.x == 0) carry_s = 0;
    __syncthreads();
    for (int base = 0; base < NN; base += 1024) {
        int i = base + threadIdx.x;
        int v = (i < NN) ? cnt[i] : 0;
        int x = v;
        #pragma unroll
        for (int off = 1; off < 64; off <<= 1) {
            int y = __shfl_up(x, off, 64);
            if (lane >= off) x += y;
        }
        if (lane == 63) wsum[wid] = x;
        __syncthreads();
        if (wid == 0 && lane < 16) {
            int s = wsum[lane];
            #pragma unroll
            for (int off = 1; off < 16; off <<= 1) {
                int y = __shfl_up(s, off, 64);
                if (lane >= off) s += y;
            }
            wsum[lane] = s;
        }
        __syncthreads();
        int woff = (wid > 0) ? wsum[wid - 1] : 0;
        int excl = x - v + woff + carry_s;
        if (i < NN) { start[i] = excl; cursor[i] = excl; }
        __syncthreads();
        if (threadIdx.x == 1023) carry_s += wsum[15];
        __syncthreads();
    }
    if (threadIdx.x == 0) start[NN] = NE;
}

// ---------------- sort: scatter -- also pre-permute esrc/eattr into sorted order
__global__ __launch_bounds__(256) void k_scatter(const int* __restrict__ edst,
                                                 const int* __restrict__ esrc,
                                                 const float* __restrict__ eattr,
                                                 int* __restrict__ cursor,
                                                 int* __restrict__ pos_arr,
                                                 int* __restrict__ esrc_s,
                                                 float4* __restrict__ eattr_s) {
    int e = blockIdx.x * blockDim.x + threadIdx.x;
    if (e >= NE) return;
    int p = atomicAdd(&cursor[edst[e]], 1);
    pos_arr[e] = p;
    esrc_s[p]  = esrc[e];
    eattr_s[p] = *(const float4*)(eattr + (size_t)e * 4);
}

// ---------------- K2a: MFMA edge-weight GEMM (writes wbuf in SORTED order) ----
__global__ __launch_bounds__(256, 2) void k_edgew_mfma(
    const float* __restrict__ ele,
    const float* __restrict__ Wfc1, const unsigned short* __restrict__ Wfragb,
    const int* __restrict__ pos_arr,
    unsigned short* __restrict__ wbuf)
{
    __shared__ float ele_s[640];
    __shared__ char  hA[64 * 256];      // [row=edge][128 bf16], byte ^= (row&7)<<4

    int tid  = threadIdx.x;
    int lane = tid & 63;
    int w    = tid >> 6;
    int e0   = blockIdx.x * 64;

    for (int idx = tid; idx < 640; idx += 256)
        ele_s[idx] = ele[(size_t)e0 * 10 + idx];
    __syncthreads();

    #pragma unroll 1
    for (int it = 0; it < 25; ++it) {
        int t2 = tid + it * 256;
        int e_loc = t2 & 63;
        int j = t2 >> 6;
        const float* elp = ele_s + e_loc * 10;
        float acc = 0.f;
        #pragma unroll
        for (int k = 0; k < 10; ++k) acc += elp[k] * Wfc1[k * 100 + j];
        float hv = acc / (1.f + __expf(-acc));
        int col2 = j * 2;
        *(unsigned short*)(hA + e_loc * 256 + (col2 ^ ((e_loc & 7) << 4))) = f2bf(hv);
    }
    for (int idx = tid; idx < 64 * 28; idx += 256) {
        int e_loc = idx / 28;
        int col2 = (100 + (idx - e_loc * 28)) * 2;
        *(unsigned short*)(hA + e_loc * 256 + (col2 ^ ((e_loc & 7) << 4))) = 0;
    }
    __syncthreads();

    const bf16x8* Wv = (const bf16x8*)Wfragb;
    bf16x8 bfr[3][4];
    #pragma unroll
    for (int nt2 = 0; nt2 < 3; ++nt2)
        #pragma unroll
        for (int ks = 0; ks < 4; ++ks)
            bfr[nt2][ks] = Wv[(((w * 3 + nt2) * 4) + ks) * 64 + lane];

    f32x4 acc[4][3];
    #pragma unroll
    for (int mt = 0; mt < 4; ++mt)
        #pragma unroll
        for (int nt2 = 0; nt2 < 3; ++nt2)
            acc[mt][nt2] = (f32x4)0.f;

    #pragma unroll
    for (int mt = 0; mt < 4; ++mt) {
        int row = mt * 16 + (lane & 15);
        #pragma unroll
        for (int ks = 0; ks < 4; ++ks) {
            int kb = ks * 64 + ((lane >> 4) << 4);
            bf16x8 a = *(const bf16x8*)(hA + row * 256 + (kb ^ ((row & 7) << 4)));
            #pragma unroll
            for (int nt2 = 0; nt2 < 3; ++nt2)
                acc[mt][nt2] = __builtin_amdgcn_mfma_f32_16x16x32_bf16(a, bfr[nt2][ks], acc[mt][nt2], 0, 0, 0);
        }
    }

    // destination rows (sorted positions) for the 16 edges this thread stores
    int posr[4][4];
    #pragma unroll
    for (int mt = 0; mt < 4; ++mt)
        #pragma unroll
        for (int r = 0; r < 4; ++r)
            posr[mt][r] = pos_arr[e0 + mt * 16 + ((lane >> 4) << 2) + r];

    #pragma unroll
    for (int mt = 0; mt < 4; ++mt) {
        #pragma unroll
        for (int nt2 = 0; nt2 < 3; ++nt2) {
            int n = w * 48 + nt2 * 16 + (lane & 15);
            #pragma unroll
            for (int r = 0; r < 4; ++r) {
                wbuf[(size_t)posr[mt][r] * 192 + n] = f2bf(acc[mt][nt2][r]);
            }
        }
    }
}

// ---------------- K2b: per-node gather — all streams sequential in i ----------
// Only remaining dependent hop: x1 row via esrc_s[i] (L2/L3-resident).
__global__ __launch_bounds__(384, 4) void k_gather(
    const int* __restrict__ start,
    const int* __restrict__ esrc_s, const float4* __restrict__ eattr_s,
    const unsigned short* __restrict__ wbuf, const float* __restrict__ x1,
    float* __restrict__ agg)
{
    int n = blockIdx.x;
    int t = threadIdx.x;
    int s0 = start[n], s1 = start[n + 1];

    int widx, gidx, kind, csel = 0;
    float scale;
    if (t < 64)       { widx = t;                gidx = t;              kind = 0; scale = Q_;   }
    else if (t < 96)  { int o = t - 64;          widx = 160 + o; gidx = 64 + 3 * o; kind = 1; scale = Q_S3; }
    else if (t < 288) { int idx = t - 96; int u = idx / 3; csel = idx - 3 * u;
                        widx = 64 + u;           gidx = u;              kind = 2; scale = Q_;   }
    else              { int idx = t - 288; int o = idx / 3; int c = idx - 3 * o;
                        widx = 128 + o;          gidx = 64 + 3 * o + c; kind = 0; scale = Q_;   }

    float a0 = 0.f, a1 = 0.f;
    int i = s0;
    for (; i + 8 <= s1; i += 8) {
        int srcb[8]; float4 eab[8]; float wvb[8];
        #pragma unroll
        for (int q = 0; q < 8; ++q) {
            srcb[q] = esrc_s[i + q];
            eab[q]  = eattr_s[i + q];
            wvb[q]  = bf2f(wbuf[(size_t)(i + q) * 192 + widx]);
        }
        float g0[8], g1[8], g2[8];
        #pragma unroll
        for (int q = 0; q < 8; ++q) {
            const float* g = x1 + (size_t)srcb[q] * 160;
            g0[q] = g[gidx];
            if (kind == 1) { g1[q] = g[gidx + 1]; g2[q] = g[gidx + 2]; }
        }
        #pragma unroll
        for (int q = 0; q < 8; ++q) {
            float* dst = (q & 1) ? &a1 : &a0;
            if (kind == 0)      *dst += wvb[q] * g0[q] * eab[q].x;
            else if (kind == 1) *dst += wvb[q] * (g0[q] * eab[q].y + g1[q] * eab[q].z + g2[q] * eab[q].w);
            else {
                float evc = (csel == 0) ? eab[q].y : ((csel == 1) ? eab[q].z : eab[q].w);
                *dst += wvb[q] * g0[q] * evc;
            }
        }
    }
    for (; i < s1; ++i) {
        int src = esrc_s[i];
        float4 ea = eattr_s[i];
        const float* g = x1 + (size_t)src * 160;
        float wv = bf2f(wbuf[(size_t)i * 192 + widx]);
        if (kind == 0)      a0 += wv * g[gidx] * ea.x;
        else if (kind == 1) a0 += wv * (g[gidx] * ea.y + g[gidx + 1] * ea.z + g[gidx + 2] * ea.w);
        else {
            float evc = (csel == 0) ? ea.y : ((csel == 1) ? ea.z : ea.w);
            a0 += wv * g[gidx] * evc;
        }
    }

    agg[(size_t)n * 384 + t] = (a0 + a1) * scale;
}

// ---------------- K3: fused l2+l3 double-MFMA ---------------------------------
__global__ __launch_bounds__(256, 2) void k_l23(
    const float* __restrict__ agg, const float* __restrict__ attr,
    const float* __restrict__ cattr, const float* __restrict__ sym,
    const unsigned short* __restrict__ WsabF, const unsigned short* __restrict__ WvabF,
    const unsigned short* __restrict__ Wl3sF, const unsigned short* __restrict__ Wl3vF,
    float* __restrict__ out)
{
    __shared__ char A1[64 * 512];   // rows padded to 512B so XOR swizzle stays in-row
    __shared__ char A2[64 * 256];

    int slot = blockIdx.y;
    int cc   = slot - 1;
    int n0   = blockIdx.x * 64;
    int tid  = threadIdx.x, lane = tid & 63, w = tid >> 6;

    for (int idx = tid; idx < 64 * 96; idx += 256) {
        int r = idx / 96, km = idx - r * 96;
        int n = n0 + r;
        float a = 0.f, cv = 0.f, val = 0.f;
        if (n < NN) {
            a = attr[n]; cv = cattr[n];
            int src = (slot == 0) ? km : (96 + 3 * km + cc);
            val = agg[(size_t)n * 384 + src];
        }
        int sw = (r & 7) << 4;
        *(unsigned short*)(A1 + r * 512 + ((2 * km) ^ sw))         = f2bf(a  * val);
        *(unsigned short*)(A1 + r * 512 + ((192 + 2 * km) ^ sw))   = f2bf(cv * val);
    }
    __syncthreads();

    const unsigned short* Bf = (slot == 0) ? WsabF : WvabF;
    f32x4 acc1[6];
    #pragma unroll
    for (int nt = 0; nt < 6; ++nt) acc1[nt] = (f32x4)0.f;

    int arow = w * 16 + (lane & 15);
    int asw  = (arow & 7) << 4;
    #pragma unroll
    for (int ks = 0; ks < 6; ++ks) {
        int kb = ks * 64 + ((lane >> 4) << 4);
        bf16x8 af = *(const bf16x8*)(A1 + arow * 512 + (kb ^ asw));
        #pragma unroll
        for (int nt = 0; nt < 6; ++nt) {
            bf16x8 bfrag = *(const bf16x8*)(Bf + (size_t)(((nt * 6 + ks) * 64) + lane) * 8);
            acc1[nt] = __builtin_amdgcn_mfma_f32_16x16x32_bf16(af, bfrag, acc1[nt], 0, 0, 0);
        }
    }

    #pragma unroll
    for (int nt = 0; nt < 6; ++nt) {
        int ncol2 = (nt * 16 + (lane & 15)) * 2;
        #pragma unroll
        for (int r = 0; r < 4; ++r) {
            int row = w * 16 + ((lane >> 4) << 2) + r;
            *(unsigned short*)(A2 + row * 256 + (ncol2 ^ ((row & 7) << 4))) = f2bf(acc1[nt][r]);
        }
    }

    // RAW hazard fence (fixed R9's intermittent post-timing divergence)
    __syncthreads();

    int NT2 = (slot == 0) ? 4 : 2;
    const unsigned short* B2 = (slot == 0) ? Wl3sF : Wl3vF;
    f32x4 acc2[4];
    #pragma unroll
    for (int nt2 = 0; nt2 < 4; ++nt2) acc2[nt2] = (f32x4)0.f;

    #pragma unroll
    for (int ks = 0; ks < 3; ++ks) {
        int kb = ks * 64 + ((lane >> 4) << 4);
        bf16x8 a2 = *(const bf16x8*)(A2 + arow * 256 + (kb ^ ((arow & 7) << 4)));
        #pragma unroll
        for (int nt2 = 0; nt2 < 4; ++nt2) {
            if (nt2 < NT2) {
                bf16x8 b2 = *(const bf16x8*)(B2 + (size_t)(((nt2 * 3 + ks) * 64) + lane) * 8);
                acc2[nt2] = __builtin_amdgcn_mfma_f32_16x16x32_bf16(a2, b2, acc2[nt2], 0, 0, 0);
            }
        }
    }

    #pragma unroll
    for (int r = 0; r < 4; ++r) {
        int n = n0 + w * 16 + ((lane >> 4) << 2) + r;
        if (n >= NN) continue;
        float sv = C_X_ * sym[n];
        #pragma unroll
        for (int nt2 = 0; nt2 < 4; ++nt2) {
            if (nt2 < NT2) {
                int col = nt2 * 16 + (lane & 15);
                int d = (slot == 0) ? col : (64 + 3 * col + cc);
                out[(size_t)n * 160 + d] += sv * acc2[nt2][r];
            }
        }
    }
}

extern "C" void kernel_launch(void* const* d_in, const int* in_sizes, int n_in,
                              void* d_out, int out_size, void* d_ws, size_t ws_size,
                              hipStream_t stream) {
    const float* ni    = (const float*)d_in[0];
    const float* attr  = (const float*)d_in[1];
    const float* cattr = (const float*)d_in[2];
    const float* sym   = (const float*)d_in[3];
    const float* eattr = (const float*)d_in[4];
    const float* ele   = (const float*)d_in[5];
    const int*   esrc  = (const int*)d_in[6];
    const int*   edst  = (const int*)d_in[7];
    const float* Ws_sc_a = (const float*)d_in[8];
    const float* Wv_sc_a = (const float*)d_in[9];
    const float* Ws_sc_c = (const float*)d_in[10];
    const float* Wv_sc_c = (const float*)d_in[11];
    const float* Ws_l1_a = (const float*)d_in[12];
    const float* Wv_l1_a = (const float*)d_in[13];
    const float* Ws_l1_c = (const float*)d_in[14];
    const float* Wv_l1_c = (const float*)d_in[15];
    const float* Wfc1    = (const float*)d_in[16];
    const float* Wfc2    = (const float*)d_in[17];
    const float* Ws_l2_a = (const float*)d_in[18];
    const float* Wv_l2_a = (const float*)d_in[19];
    const float* Ws_l2_c = (const float*)d_in[20];
    const float* Wv_l2_c = (const float*)d_in[21];
    const float* Ws_l3   = (const float*)d_in[22];
    const float* Wv_l3   = (const float*)d_in[23];

    float* out = (float*)d_out;
    float* ws  = (float*)d_ws;
    float* x1  = ws;                          // NN*160
    float* agg = x1 + (size_t)NN * 160;       // NN*384
    float* W4s = agg + (size_t)NN * 384;      // 16384
    float* W4v = W4s + 16384;                 // 4096
    unsigned short* Wfragb = (unsigned short*)(W4v + 4096);  // 24576
    unsigned short* WsabF  = Wfragb + 24576;                 // 18432
    unsigned short* WvabF  = WsabF + 18432;                  // 18432
    unsigned short* Wl3sF  = WvabF + 18432;                  // 6144
    unsigned short* Wl3vF  = Wl3sF + 6144;                   // 3072
    float4* eattr_s = (float4*)(Wl3vF + 3072);               // NE float4 (16B-aligned)
    unsigned short* wbuf = (unsigned short*)(eattr_s + NE);  // NE*192
    int* cnt     = (int*)(wbuf + (size_t)NE * 192);          // NN
    int* start_  = cnt + NN;                                 // NN+1
    int* cursor  = start_ + NN + 1;                          // NN
    int* pos_arr = cursor + NN;                              // NE
    int* esrc_s  = pos_arr + NE;                             // NE

    size_t need = ((size_t)NN * 160 + (size_t)NN * 384 + 16384 + 4096) * 4
                + ((size_t)24576 + 18432 + 18432 + 6144 + 3072 + (size_t)NE * 192) * 2
                + (size_t)NE * 16
                + ((size_t)NN * 3 + 1 + (size_t)NE * 2) * 4;
    if (ws_size < need) return;

    k_pack<<<(75776 + 255) / 256, 256, 0, stream>>>(
        Wfc2,
        Ws_sc_a, Ws_sc_c, Ws_l1_a, Ws_l1_c, W4s,
        Wv_sc_a, Wv_sc_c, Wv_l1_a, Wv_l1_c, W4v,
        Ws_l2_a, Ws_l2_c, Wv_l2_a, Wv_l2_c,
        Ws_l3, Wv_l3,
        Wfragb, WsabF, WvabF, Wl3sF, Wl3vF);

    k_node_prep<<<(NN * 160 + 255) / 256, 256, 0, stream>>>(
        ni, attr, cattr, W4s, W4v, x1, out);

    hipMemsetAsync(cnt, 0, (size_t)NN * sizeof(int), stream);
    k_hist<<<(NE + 255) / 256, 256, 0, stream>>>(edst, cnt);
    k_scan<<<1, 1024, 0, stream>>>(cnt, start_, cursor);
    k_scatter<<<(NE + 255) / 256, 256, 0, stream>>>(edst, esrc, eattr,
                                                    cursor, pos_arr, esrc_s, eattr_s);
    k_edgew_mfma<<<NE / 64, 256, 0, stream>>>(ele, Wfc1, Wfragb, pos_arr, wbuf);
    k_gather<<<NN, 384, 0, stream>>>(start_, esrc_s, eattr_s, wbuf, x1, agg);

    k_l23<<<dim3((NN + 63) / 64, 4), 256, 0, stream>>>(
        agg, attr, cattr, sym, WsabF, WvabF, Wl3sF, Wl3vF, out);
}

// Round 13
// 459.968 us; speedup vs baseline: 1.2635x; 1.2635x over previous
//
#include <hip/hip_runtime.h>
#include <math.h>

#define NN 25000
#define NE 400000

static constexpr float C_S_ = 0.3826834323650898f;   // sin(pi/8)
static constexpr float C_X_ = 0.9238795325112867f;   // cos(pi/8)
static constexpr float Q_   = 0.25f;                 // 1/sqrt(16)
static constexpr float Q_S3 = 0.25f * 0.5773502691896258f; // Q / sqrt(3)

typedef __attribute__((ext_vector_type(8))) short bf16x8;
typedef __attribute__((ext_vector_type(4))) float f32x4;

__device__ inline unsigned short f2bf(float f) {
    union { float f; unsigned u; } v; v.f = f;
    unsigned r = v.u + 0x7fffu + ((v.u >> 16) & 1u);   // RNE
    return (unsigned short)(r >> 16);
}
__device__ inline float bf2f(unsigned short s) {
    union { unsigned u; float f; } v; v.u = ((unsigned)s) << 16;
    return v.f;
}

// ---------------- K0: pack weights (all bf16 MFMA B-fragments) -----------------
// Frag layout [nt][ks][l<64][i<8]: element k = ks*32+(l>>4)*8+i, n = nt*16+(l&15).
__global__ void k_pack(const float* __restrict__ Wfc2,
                       const float* __restrict__ Wsa, const float* __restrict__ Wsc,
                       const float* __restrict__ W1sa, const float* __restrict__ W1sc,
                       const float* __restrict__ Wva, const float* __restrict__ Wvc,
                       const float* __restrict__ W1va, const float* __restrict__ W1vc,
                       const float* __restrict__ Wl2sa, const float* __restrict__ Wl2sc,
                       const float* __restrict__ Wl2va, const float* __restrict__ Wl2vc,
                       const float* __restrict__ Wl3s, const float* __restrict__ Wl3v,
                       unsigned short* __restrict__ Wfragb,
                       unsigned short* __restrict__ WsabF, unsigned short* __restrict__ WvabF,
                       unsigned short* __restrict__ Wl3sF, unsigned short* __restrict__ Wl3vF,
                       unsigned short* __restrict__ WscF, unsigned short* __restrict__ W1sF,
                       unsigned short* __restrict__ WvcF, unsigned short* __restrict__ W1vF)
{
    int t = blockIdx.x * blockDim.x + threadIdx.x;
    if (t < 24576) {   // Wfc2 (K=100 pad 128, N=192)
        int i = t & 7, l = (t >> 3) & 63, ks = (t >> 9) & 3, nt = t >> 11;
        int k = ks * 32 + ((l >> 4) << 3) + i;
        int n = nt * 16 + (l & 15);
        Wfragb[t] = (k < 100) ? f2bf(Wfc2[k * 192 + n]) : (unsigned short)0;
        return;
    }
    t -= 24576;
    if (t < 18432) {   // [Wl2sa;Wl2sc] K=192 N=96
        int i = t & 7, l = (t >> 3) & 63, rem = t >> 9;
        int ks = rem % 6, nt = rem / 6;
        int k = ks * 32 + ((l >> 4) << 3) + i;
        int n = nt * 16 + (l & 15);
        WsabF[t] = f2bf(k < 96 ? Wl2sa[k * 96 + n] : Wl2sc[(k - 96) * 96 + n]);
        return;
    }
    t -= 18432;
    if (t < 18432) {   // [Wl2va;Wl2vc]
        int i = t & 7, l = (t >> 3) & 63, rem = t >> 9;
        int ks = rem % 6, nt = rem / 6;
        int k = ks * 32 + ((l >> 4) << 3) + i;
        int n = nt * 16 + (l & 15);
        WvabF[t] = f2bf(k < 96 ? Wl2va[k * 96 + n] : Wl2vc[(k - 96) * 96 + n]);
        return;
    }
    t -= 18432;
    if (t < 6144) {    // Ws_l3 K=96 N=64
        int i = t & 7, l = (t >> 3) & 63, rem = t >> 9;
        int ks = rem % 3, nt = rem / 3;
        int k = ks * 32 + ((l >> 4) << 3) + i;
        int n = nt * 16 + (l & 15);
        Wl3sF[t] = f2bf(Wl3s[k * 64 + n]);
        return;
    }
    t -= 6144;
    if (t < 3072) {    // Wv_l3 K=96 N=32
        int i = t & 7, l = (t >> 3) & 63, rem = t >> 9;
        int ks = rem % 3, nt = rem / 3;
        int k = ks * 32 + ((l >> 4) << 3) + i;
        int n = nt * 16 + (l & 15);
        Wl3vF[t] = f2bf(Wl3v[k * 32 + n]);
        return;
    }
    t -= 3072;
    if (t < 8192) {    // [Wsa;Wsc] K=128 N=64  (skip-scalar)
        int i = t & 7, l = (t >> 3) & 63, rem = t >> 9;
        int ks = rem & 3, nt = rem >> 2;
        int k = ks * 32 + ((l >> 4) << 3) + i;
        int n = nt * 16 + (l & 15);
        WscF[t] = f2bf(k < 64 ? Wsa[k * 64 + n] : Wsc[(k - 64) * 64 + n]);
        return;
    }
    t -= 8192;
    if (t < 8192) {    // [W1sa;W1sc] K=128 N=64  (l1-scalar)
        int i = t & 7, l = (t >> 3) & 63, rem = t >> 9;
        int ks = rem & 3, nt = rem >> 2;
        int k = ks * 32 + ((l >> 4) << 3) + i;
        int n = nt * 16 + (l & 15);
        W1sF[t] = f2bf(k < 64 ? W1sa[k * 64 + n] : W1sc[(k - 64) * 64 + n]);
        return;
    }
    t -= 8192;
    if (t < 2048) {    // [Wva;Wvc] K=64 N=32  (skip-vector)
        int i = t & 7, l = (t >> 3) & 63, rem = t >> 9;
        int ks = rem & 1, nt = rem >> 1;
        int k = ks * 32 + ((l >> 4) << 3) + i;
        int n = nt * 16 + (l & 15);
        WvcF[t] = f2bf(k < 32 ? Wva[k * 32 + n] : Wvc[(k - 32) * 32 + n]);
        return;
    }
    t -= 2048;
    if (t < 2048) {    // [W1va;W1vc] K=64 N=32  (l1-vector)
        int i = t & 7, l = (t >> 3) & 63, rem = t >> 9;
        int ks = rem & 1, nt = rem >> 1;
        int k = ks * 32 + ((l >> 4) << 3) + i;
        int n = nt * 16 + (l & 15);
        W1vF[t] = f2bf(k < 32 ? W1va[k * 32 + n] : W1vc[(k - 32) * 32 + n]);
        return;
    }
}

// ---------------- K1: node prep via MFMA (k_l23 pattern) -----------------------
// grid (391,4): slot 0 scalar (K=128), slot 1..3 vector comp cc (K=64).
// A1 = [a*x | c*x]; B1=[Wsc_pair] -> out (skip, *C_S), B2=[Wl1_pair] -> x1.
__global__ __launch_bounds__(256, 2) void k_np_mfma(
    const float* __restrict__ ni, const float* __restrict__ attr, const float* __restrict__ cattr,
    const unsigned short* __restrict__ WscF, const unsigned short* __restrict__ W1sF,
    const unsigned short* __restrict__ WvcF, const unsigned short* __restrict__ W1vF,
    float* __restrict__ x1, float* __restrict__ out)
{
    __shared__ char A1[64 * 256];
    int slot = blockIdx.y, cc = slot - 1;
    int n0 = blockIdx.x * 64;
    int tid = threadIdx.x, lane = tid & 63, w = tid >> 6;

    if (slot == 0) {
        for (int idx = tid; idx < 64 * 64; idx += 256) {
            int r = idx >> 6, k = idx & 63;
            int n = n0 + r;
            float a = 0.f, cv = 0.f, val = 0.f;
            if (n < NN) { a = attr[n]; cv = cattr[n]; val = ni[(size_t)n * 160 + k]; }
            int sw = (r & 7) << 4;
            *(unsigned short*)(A1 + r * 256 + ((2 * k) ^ sw))       = f2bf(a  * val);
            *(unsigned short*)(A1 + r * 256 + ((128 + 2 * k) ^ sw)) = f2bf(cv * val);
        }
    } else {
        for (int idx = tid; idx < 64 * 32; idx += 256) {
            int r = idx >> 5, u = idx & 31;
            int n = n0 + r;
            float a = 0.f, cv = 0.f, val = 0.f;
            if (n < NN) { a = attr[n]; cv = cattr[n]; val = ni[(size_t)n * 160 + 64 + 3 * u + cc]; }
            int sw = (r & 7) << 4;
            *(unsigned short*)(A1 + r * 128 + ((2 * u) ^ sw))      = f2bf(a  * val);
            *(unsigned short*)(A1 + r * 128 + ((64 + 2 * u) ^ sw)) = f2bf(cv * val);
        }
    }
    __syncthreads();

    int arow = w * 16 + (lane & 15);
    int asw  = (arow & 7) << 4;

    if (slot == 0) {
        f32x4 accS[4], accX[4];
        #pragma unroll
        for (int nt = 0; nt < 4; ++nt) { accS[nt] = (f32x4)0.f; accX[nt] = (f32x4)0.f; }
        #pragma unroll
        for (int ks = 0; ks < 4; ++ks) {
            int kb = ks * 64 + ((lane >> 4) << 4);
            bf16x8 af = *(const bf16x8*)(A1 + arow * 256 + (kb ^ asw));
            #pragma unroll
            for (int nt = 0; nt < 4; ++nt) {
                bf16x8 b1 = *(const bf16x8*)(WscF + (size_t)(((nt * 4 + ks) * 64) + lane) * 8);
                bf16x8 b2 = *(const bf16x8*)(W1sF + (size_t)(((nt * 4 + ks) * 64) + lane) * 8);
                accS[nt] = __builtin_amdgcn_mfma_f32_16x16x32_bf16(af, b1, accS[nt], 0, 0, 0);
                accX[nt] = __builtin_amdgcn_mfma_f32_16x16x32_bf16(af, b2, accX[nt], 0, 0, 0);
            }
        }
        #pragma unroll
        for (int r = 0; r < 4; ++r) {
            int n = n0 + w * 16 + ((lane >> 4) << 2) + r;
            if (n >= NN) continue;
            #pragma unroll
            for (int nt = 0; nt < 4; ++nt) {
                int col = nt * 16 + (lane & 15);
                out[(size_t)n * 160 + col] = C_S_ * accS[nt][r];
                x1[(size_t)n * 160 + col]  = accX[nt][r];
            }
        }
    } else {
        f32x4 accS[2], accX[2];
        #pragma unroll
        for (int nt = 0; nt < 2; ++nt) { accS[nt] = (f32x4)0.f; accX[nt] = (f32x4)0.f; }
        #pragma unroll
        for (int ks = 0; ks < 2; ++ks) {
            int kb = ks * 64 + ((lane >> 4) << 4);
            bf16x8 af = *(const bf16x8*)(A1 + arow * 128 + (kb ^ asw));
            #pragma unroll
            for (int nt = 0; nt < 2; ++nt) {
                bf16x8 b1 = *(const bf16x8*)(WvcF + (size_t)(((nt * 2 + ks) * 64) + lane) * 8);
                bf16x8 b2 = *(const bf16x8*)(W1vF + (size_t)(((nt * 2 + ks) * 64) + lane) * 8);
                accS[nt] = __builtin_amdgcn_mfma_f32_16x16x32_bf16(af, b1, accS[nt], 0, 0, 0);
                accX[nt] = __builtin_amdgcn_mfma_f32_16x16x32_bf16(af, b2, accX[nt], 0, 0, 0);
            }
        }
        #pragma unroll
        for (int r = 0; r < 4; ++r) {
            int n = n0 + w * 16 + ((lane >> 4) << 2) + r;
            if (n >= NN) continue;
            #pragma unroll
            for (int nt = 0; nt < 2; ++nt) {
                int o = nt * 16 + (lane & 15);
                int d = 64 + 3 * o + cc;
                out[(size_t)n * 160 + d] = C_S_ * accS[nt][r];
                x1[(size_t)n * 160 + d]  = accX[nt][r];
            }
        }
    }
}

// ---------------- sort: histogram ---------------------------------------------
__global__ __launch_bounds__(256) void k_hist(const int* __restrict__ edst, int* __restrict__ cnt) {
    int e = blockIdx.x * blockDim.x + threadIdx.x;
    if (e >= NE) return;
    atomicAdd(&cnt[edst[e]], 1);
}

// ---------------- sort: single-block exclusive scan over NN counts ------------
__global__ __launch_bounds__(1024) void k_scan(const int* __restrict__ cnt,
                                               int* __restrict__ start, int* __restrict__ cursor) {
    __shared__ int wsum[16];
    __shared__ int carry_s;
    int lane = threadIdx.x & 63, wid = threadIdx.x >> 6;
    if (threadIdx.x == 0) carry_s = 0;
    __syncthreads();
    for (int base = 0; base < NN; base += 1024) {
        int i = base + threadIdx.x;
        int v = (i < NN) ? cnt[i] : 0;
        int x = v;
        #pragma unroll
        for (int off = 1; off < 64; off <<= 1) {
            int y = __shfl_up(x, off, 64);
            if (lane >= off) x += y;
        }
        if (lane == 63) wsum[wid] = x;
        __syncthreads();
        if (wid == 0 && lane < 16) {
            int s = wsum[lane];
            #pragma unroll
            for (int off = 1; off < 16; off <<= 1) {
                int y = __shfl_up(s, off, 64);
                if (lane >= off) s += y;
            }
            wsum[lane] = s;
        }
        __syncthreads();
        int woff = (wid > 0) ? wsum[wid - 1] : 0;
        int excl = x - v + woff + carry_s;
        if (i < NN) { start[i] = excl; cursor[i] = excl; }
        __syncthreads();
        if (threadIdx.x == 1023) carry_s += wsum[15];
        __syncthreads();
    }
    if (threadIdx.x == 0) start[NN] = NE;
}

// ---------------- sort: scatter -- also pre-permute esrc/eattr into sorted order
__global__ __launch_bounds__(256) void k_scatter(const int* __restrict__ edst,
                                                 const int* __restrict__ esrc,
                                                 const float* __restrict__ eattr,
                                                 int* __restrict__ cursor,
                                                 int* __restrict__ pos_arr,
                                                 int* __restrict__ esrc_s,
                                                 float4* __restrict__ eattr_s) {
    int e = blockIdx.x * blockDim.x + threadIdx.x;
    if (e >= NE) return;
    int p = atomicAdd(&cursor[edst[e]], 1);
    pos_arr[e] = p;
    esrc_s[p]  = esrc[e];
    eattr_s[p] = *(const float4*)(eattr + (size_t)e * 4);
}

// ---------------- K2a: MFMA edge-weight GEMM (writes wbuf in SORTED order) ----
__global__ __launch_bounds__(256, 2) void k_edgew_mfma(
    const float* __restrict__ ele,
    const float* __restrict__ Wfc1, const unsigned short* __restrict__ Wfragb,
    const int* __restrict__ pos_arr,
    unsigned short* __restrict__ wbuf)
{
    __shared__ float ele_s[640];
    __shared__ char  hA[64 * 256];      // [row=edge][128 bf16], byte ^= (row&7)<<4

    int tid  = threadIdx.x;
    int lane = tid & 63;
    int w    = tid >> 6;
    int e0   = blockIdx.x * 64;

    for (int idx = tid; idx < 640; idx += 256)
        ele_s[idx] = ele[(size_t)e0 * 10 + idx];
    __syncthreads();

    #pragma unroll 1
    for (int it = 0; it < 25; ++it) {
        int t2 = tid + it * 256;
        int e_loc = t2 & 63;
        int j = t2 >> 6;
        const float* elp = ele_s + e_loc * 10;
        float acc = 0.f;
        #pragma unroll
        for (int k = 0; k < 10; ++k) acc += elp[k] * Wfc1[k * 100 + j];
        float hv = acc / (1.f + __expf(-acc));
        int col2 = j * 2;
        *(unsigned short*)(hA + e_loc * 256 + (col2 ^ ((e_loc & 7) << 4))) = f2bf(hv);
    }
    for (int idx = tid; idx < 64 * 28; idx += 256) {
        int e_loc = idx / 28;
        int col2 = (100 + (idx - e_loc * 28)) * 2;
        *(unsigned short*)(hA + e_loc * 256 + (col2 ^ ((e_loc & 7) << 4))) = 0;
    }
    __syncthreads();

    const bf16x8* Wv = (const bf16x8*)Wfragb;
    bf16x8 bfr[3][4];
    #pragma unroll
    for (int nt2 = 0; nt2 < 3; ++nt2)
        #pragma unroll
        for (int ks = 0; ks < 4; ++ks)
            bfr[nt2][ks] = Wv[(((w * 3 + nt2) * 4) + ks) * 64 + lane];

    f32x4 acc[4][3];
    #pragma unroll
    for (int mt = 0; mt < 4; ++mt)
        #pragma unroll
        for (int nt2 = 0; nt2 < 3; ++nt2)
            acc[mt][nt2] = (f32x4)0.f;

    #pragma unroll
    for (int mt = 0; mt < 4; ++mt) {
        int row = mt * 16 + (lane & 15);
        #pragma unroll
        for (int ks = 0; ks < 4; ++ks) {
            int kb = ks * 64 + ((lane >> 4) << 4);
            bf16x8 a = *(const bf16x8*)(hA + row * 256 + (kb ^ ((row & 7) << 4)));
            #pragma unroll
            for (int nt2 = 0; nt2 < 3; ++nt2)
                acc[mt][nt2] = __builtin_amdgcn_mfma_f32_16x16x32_bf16(a, bfr[nt2][ks], acc[mt][nt2], 0, 0, 0);
        }
    }

    int posr[4][4];
    #pragma unroll
    for (int mt = 0; mt < 4; ++mt)
        #pragma unroll
        for (int r = 0; r < 4; ++r)
            posr[mt][r] = pos_arr[e0 + mt * 16 + ((lane >> 4) << 2) + r];

    #pragma unroll
    for (int mt = 0; mt < 4; ++mt) {
        #pragma unroll
        for (int nt2 = 0; nt2 < 3; ++nt2) {
            int n = w * 48 + nt2 * 16 + (lane & 15);
            #pragma unroll
            for (int r = 0; r < 4; ++r) {
                wbuf[(size_t)posr[mt][r] * 192 + n] = f2bf(acc[mt][nt2][r]);
            }
        }
    }
}

// ---------------- K2b: per-node gather — all streams sequential in i ----------
__global__ __launch_bounds__(384, 4) void k_gather(
    const int* __restrict__ start,
    const int* __restrict__ esrc_s, const float4* __restrict__ eattr_s,
    const unsigned short* __restrict__ wbuf, const float* __restrict__ x1,
    float* __restrict__ agg)
{
    int n = blockIdx.x;
    int t = threadIdx.x;
    int s0 = start[n], s1 = start[n + 1];

    int widx, gidx, kind, csel = 0;
    float scale;
    if (t < 64)       { widx = t;                gidx = t;              kind = 0; scale = Q_;   }
    else if (t < 96)  { int o = t - 64;          widx = 160 + o; gidx = 64 + 3 * o; kind = 1; scale = Q_S3; }
    else if (t < 288) { int idx = t - 96; int u = idx / 3; csel = idx - 3 * u;
                        widx = 64 + u;           gidx = u;              kind = 2; scale = Q_;   }
    else              { int idx = t - 288; int o = idx / 3; int c = idx - 3 * o;
                        widx = 128 + o;          gidx = 64 + 3 * o + c; kind = 0; scale = Q_;   }

    float a0 = 0.f, a1 = 0.f;
    int i = s0;
    for (; i + 8 <= s1; i += 8) {
        int srcb[8]; float4 eab[8]; float wvb[8];
        #pragma unroll
        for (int q = 0; q < 8; ++q) {
            srcb[q] = esrc_s[i + q];
            eab[q]  = eattr_s[i + q];
            wvb[q]  = bf2f(wbuf[(size_t)(i + q) * 192 + widx]);
        }
        float g0[8], g1[8], g2[8];
        #pragma unroll
        for (int q = 0; q < 8; ++q) {
            const float* g = x1 + (size_t)srcb[q] * 160;
            g0[q] = g[gidx];
            if (kind == 1) { g1[q] = g[gidx + 1]; g2[q] = g[gidx + 2]; }
        }
        #pragma unroll
        for (int q = 0; q < 8; ++q) {
            float* dst = (q & 1) ? &a1 : &a0;
            if (kind == 0)      *dst += wvb[q] * g0[q] * eab[q].x;
            else if (kind == 1) *dst += wvb[q] * (g0[q] * eab[q].y + g1[q] * eab[q].z + g2[q] * eab[q].w);
            else {
                float evc = (csel == 0) ? eab[q].y : ((csel == 1) ? eab[q].z : eab[q].w);
                *dst += wvb[q] * g0[q] * evc;
            }
        }
    }
    for (; i < s1; ++i) {
        int src = esrc_s[i];
        float4 ea = eattr_s[i];
        const float* g = x1 + (size_t)src * 160;
        float wv = bf2f(wbuf[(size_t)i * 192 + widx]);
        if (kind == 0)      a0 += wv * g[gidx] * ea.x;
        else if (kind == 1) a0 += wv * (g[gidx] * ea.y + g[gidx + 1] * ea.z + g[gidx + 2] * ea.w);
        else {
            float evc = (csel == 0) ? ea.y : ((csel == 1) ? ea.z : ea.w);
            a0 += wv * g[gidx] * evc;
        }
    }

    agg[(size_t)n * 384 + t] = (a0 + a1) * scale;
}

// ---------------- K3: fused l2+l3 double-MFMA ---------------------------------
__global__ __launch_bounds__(256, 2) void k_l23(
    const float* __restrict__ agg, const float* __restrict__ attr,
    const float* __restrict__ cattr, const float* __restrict__ sym,
    const unsigned short* __restrict__ WsabF, const unsigned short* __restrict__ WvabF,
    const unsigned short* __restrict__ Wl3sF, const unsigned short* __restrict__ Wl3vF,
    float* __restrict__ out)
{
    __shared__ char A1[64 * 512];   // rows padded to 512B so XOR swizzle stays in-row
    __shared__ char A2[64 * 256];

    int slot = blockIdx.y;
    int cc   = slot - 1;
    int n0   = blockIdx.x * 64;
    int tid  = threadIdx.x, lane = tid & 63, w = tid >> 6;

    for (int idx = tid; idx < 64 * 96; idx += 256) {
        int r = idx / 96, km = idx - r * 96;
        int n = n0 + r;
        float a = 0.f, cv = 0.f, val = 0.f;
        if (n < NN) {
            a = attr[n]; cv = cattr[n];
            int src = (slot == 0) ? km : (96 + 3 * km + cc);
            val = agg[(size_t)n * 384 + src];
        }
        int sw = (r & 7) << 4;
        *(unsigned short*)(A1 + r * 512 + ((2 * km) ^ sw))         = f2bf(a  * val);
        *(unsigned short*)(A1 + r * 512 + ((192 + 2 * km) ^ sw))   = f2bf(cv * val);
    }
    __syncthreads();

    const unsigned short* Bf = (slot == 0) ? WsabF : WvabF;
    f32x4 acc1[6];
    #pragma unroll
    for (int nt = 0; nt < 6; ++nt) acc1[nt] = (f32x4)0.f;

    int arow = w * 16 + (lane & 15);
    int asw  = (arow & 7) << 4;
    #pragma unroll
    for (int ks = 0; ks < 6; ++ks) {
        int kb = ks * 64 + ((lane >> 4) << 4);
        bf16x8 af = *(const bf16x8*)(A1 + arow * 512 + (kb ^ asw));
        #pragma unroll
        for (int nt = 0; nt < 6; ++nt) {
            bf16x8 bfrag = *(const bf16x8*)(Bf + (size_t)(((nt * 6 + ks) * 64) + lane) * 8);
            acc1[nt] = __builtin_amdgcn_mfma_f32_16x16x32_bf16(af, bfrag, acc1[nt], 0, 0, 0);
        }
    }

    #pragma unroll
    for (int nt = 0; nt < 6; ++nt) {
        int ncol2 = (nt * 16 + (lane & 15)) * 2;
        #pragma unroll
        for (int r = 0; r < 4; ++r) {
            int row = w * 16 + ((lane >> 4) << 2) + r;
            *(unsigned short*)(A2 + row * 256 + (ncol2 ^ ((row & 7) << 4))) = f2bf(acc1[nt][r]);
        }
    }

    // RAW hazard fence (fixed R9's intermittent post-timing divergence)
    __syncthreads();

    int NT2 = (slot == 0) ? 4 : 2;
    const unsigned short* B2 = (slot == 0) ? Wl3sF : Wl3vF;
    f32x4 acc2[4];
    #pragma unroll
    for (int nt2 = 0; nt2 < 4; ++nt2) acc2[nt2] = (f32x4)0.f;

    #pragma unroll
    for (int ks = 0; ks < 3; ++ks) {
        int kb = ks * 64 + ((lane >> 4) << 4);
        bf16x8 a2 = *(const bf16x8*)(A2 + arow * 256 + (kb ^ ((arow & 7) << 4)));
        #pragma unroll
        for (int nt2 = 0; nt2 < 4; ++nt2) {
            if (nt2 < NT2) {
                bf16x8 b2 = *(const bf16x8*)(B2 + (size_t)(((nt2 * 3 + ks) * 64) + lane) * 8);
                acc2[nt2] = __builtin_amdgcn_mfma_f32_16x16x32_bf16(a2, b2, acc2[nt2], 0, 0, 0);
            }
        }
    }

    #pragma unroll
    for (int r = 0; r < 4; ++r) {
        int n = n0 + w * 16 + ((lane >> 4) << 2) + r;
        if (n >= NN) continue;
        float sv = C_X_ * sym[n];
        #pragma unroll
        for (int nt2 = 0; nt2 < 4; ++nt2) {
            if (nt2 < NT2) {
                int col = nt2 * 16 + (lane & 15);
                int d = (slot == 0) ? col : (64 + 3 * col + cc);
                out[(size_t)n * 160 + d] += sv * acc2[nt2][r];
            }
        }
    }
}

extern "C" void kernel_launch(void* const* d_in, const int* in_sizes, int n_in,
                              void* d_out, int out_size, void* d_ws, size_t ws_size,
                              hipStream_t stream) {
    const float* ni    = (const float*)d_in[0];
    const float* attr  = (const float*)d_in[1];
    const float* cattr = (const float*)d_in[2];
    const float* sym   = (const float*)d_in[3];
    const float* eattr = (const float*)d_in[4];
    const float* ele   = (const float*)d_in[5];
    const int*   esrc  = (const int*)d_in[6];
    const int*   edst  = (const int*)d_in[7];
    const float* Ws_sc_a = (const float*)d_in[8];
    const float* Wv_sc_a = (const float*)d_in[9];
    const float* Ws_sc_c = (const float*)d_in[10];
    const float* Wv_sc_c = (const float*)d_in[11];
    const float* Ws_l1_a = (const float*)d_in[12];
    const float* Wv_l1_a = (const float*)d_in[13];
    const float* Ws_l1_c = (const float*)d_in[14];
    const float* Wv_l1_c = (const float*)d_in[15];
    const float* Wfc1    = (const float*)d_in[16];
    const float* Wfc2    = (const float*)d_in[17];
    const float* Ws_l2_a = (const float*)d_in[18];
    const float* Wv_l2_a = (const float*)d_in[19];
    const float* Ws_l2_c = (const float*)d_in[20];
    const float* Wv_l2_c = (const float*)d_in[21];
    const float* Ws_l3   = (const float*)d_in[22];
    const float* Wv_l3   = (const float*)d_in[23];

    float* out = (float*)d_out;
    float* ws  = (float*)d_ws;
    float* x1  = ws;                          // NN*160
    float* agg = x1 + (size_t)NN * 160;       // NN*384
    unsigned short* Wfragb = (unsigned short*)(agg + (size_t)NN * 384);  // 24576
    unsigned short* WsabF  = Wfragb + 24576;                 // 18432
    unsigned short* WvabF  = WsabF + 18432;                  // 18432
    unsigned short* Wl3sF  = WvabF + 18432;                  // 6144
    unsigned short* Wl3vF  = Wl3sF + 6144;                   // 3072
    unsigned short* WscF   = Wl3vF + 3072;                   // 8192
    unsigned short* W1sF   = WscF + 8192;                    // 8192
    unsigned short* WvcF   = W1sF + 8192;                    // 2048
    unsigned short* W1vF   = WvcF + 2048;                    // 2048
    // shorts so far: 91136 -> 182272 bytes (16B-aligned: 182272/16=11392)
    float4* eattr_s = (float4*)(W1vF + 2048);                // NE float4
    unsigned short* wbuf = (unsigned short*)(eattr_s + NE);  // NE*192
    int* cnt     = (int*)(wbuf + (size_t)NE * 192);          // NN
    int* start_  = cnt + NN;                                 // NN+1
    int* cursor  = start_ + NN + 1;                          // NN
    int* pos_arr = cursor + NN;                              // NE
    int* esrc_s  = pos_arr + NE;                             // NE

    size_t need = ((size_t)NN * 160 + (size_t)NN * 384) * 4
                + ((size_t)91136 + (size_t)NE * 192) * 2
                + (size_t)NE * 16
                + ((size_t)NN * 3 + 1 + (size_t)NE * 2) * 4;
    if (ws_size < need) return;

    k_pack<<<(91136 + 255) / 256, 256, 0, stream>>>(
        Wfc2,
        Ws_sc_a, Ws_sc_c, Ws_l1_a, Ws_l1_c,
        Wv_sc_a, Wv_sc_c, Wv_l1_a, Wv_l1_c,
        Ws_l2_a, Ws_l2_c, Wv_l2_a, Wv_l2_c,
        Ws_l3, Wv_l3,
        Wfragb, WsabF, WvabF, Wl3sF, Wl3vF,
        WscF, W1sF, WvcF, W1vF);

    k_np_mfma<<<dim3((NN + 63) / 64, 4), 256, 0, stream>>>(
        ni, attr, cattr, WscF, W1sF, WvcF, W1vF, x1, out);

    hipMemsetAsync(cnt, 0, (size_t)NN * sizeof(int), stream);
    k_hist<<<(NE + 255) / 256, 256, 0, stream>>>(edst, cnt);
    k_scan<<<1, 1024, 0, stream>>>(cnt, start_, cursor);
    k_scatter<<<(NE + 255) / 256, 256, 0, stream>>>(edst, esrc, eattr,
                                                    cursor, pos_arr, esrc_s, eattr_s);
    k_edgew_mfma<<<NE / 64, 256, 0, stream>>>(ele, Wfc1, Wfragb, pos_arr, wbuf);
    k_gather<<<NN, 384, 0, stream>>>(start_, esrc_s, eattr_s, wbuf, x1, agg);

    k_l23<<<dim3((NN + 63) / 64, 4), 256, 0, stream>>>(
        agg, attr, cattr, sym, WsabF, WvabF, Wl3sF, Wl3vF, out);
}